// Round 2
// baseline (533.612 us; speedup 1.0000x reference)
//
#include <hip/hip_runtime.h>
#include <cstdint>

#define B_SZ 8192
#define D_SZ 1024
#define E_SZ 16
#define H_SZ 1024
#define MAXTILES 544   // >= sum_e ceil(count_e/128) worst case (512+16)

using short8 = __attribute__((ext_vector_type(8))) short;
using f32x4  = __attribute__((ext_vector_type(4))) float;

__device__ __forceinline__ unsigned short f2bf(float f) {
  union { float f; unsigned int u; } v; v.f = f;
  unsigned int u = v.u;
  return (unsigned short)((u + 0x7fffu + ((u >> 16) & 1u)) >> 16);  // RNE
}
__device__ __forceinline__ float bf2f(unsigned short h) {
  union { unsigned int u; float f; } v; v.u = ((unsigned int)h) << 16; return v.f;
}

__device__ __forceinline__ void async_ld16(void* lds, const void* g) {
  __builtin_amdgcn_global_load_lds(
      reinterpret_cast<const unsigned int __attribute__((address_space(1)))*>(
          reinterpret_cast<uintptr_t>(g)),
      reinterpret_cast<unsigned int __attribute__((address_space(3)))*>(
          reinterpret_cast<uintptr_t>(lds)),
      16, 0, 0);
}

// ---------------- x -> bf16, zero stats (importance/load/counts) ----------------
__global__ __launch_bounds__(256) void xcast(const float* __restrict__ x,
                                             unsigned short* __restrict__ xb,
                                             float* __restrict__ stats) {
  const size_t i = (size_t)blockIdx.x * 256 + threadIdx.x;  // float4 index
  float4 v = ((const float4*)x)[i];
  unsigned long long r = (unsigned long long)f2bf(v.x)
      | ((unsigned long long)f2bf(v.y) << 16)
      | ((unsigned long long)f2bf(v.z) << 32)
      | ((unsigned long long)f2bf(v.w) << 48);
  ((unsigned long long*)xb)[i] = r;
  if (blockIdx.x == 0 && threadIdx.x < 48) stats[threadIdx.x] = 0.0f;
}

// ---------------- expert_w (E,D,H) fp32 -> Wt (E,H,D) bf16 ----------------
__global__ __launch_bounds__(256) void wtconv(const float* __restrict__ W,
                                              unsigned short* __restrict__ Wt) {
  __shared__ float t[64][65];
  const int e  = blockIdx.z;
  const int d0 = blockIdx.x * 64;
  const int h0 = blockIdx.y * 64;
  const float* We = W + (size_t)e * D_SZ * H_SZ;
  unsigned short* Wte = Wt + (size_t)e * D_SZ * H_SZ;
  #pragma unroll
  for (int i = 0; i < 16; ++i) {
    const int idx = i * 256 + threadIdx.x;
    const int r = idx >> 6, c = idx & 63;
    t[r][c] = We[(size_t)(d0 + r) * H_SZ + h0 + c];
  }
  __syncthreads();
  #pragma unroll
  for (int i = 0; i < 16; ++i) {
    const int idx = i * 256 + threadIdx.x;
    const int r = idx >> 6, c = idx & 63;   // r = h within tile, c = d within tile
    Wte[(size_t)(h0 + r) * D_SZ + d0 + c] = f2bf(t[c][r]);
  }
}

// ---------------- clean / raw-noise logits (fp32, register-blocked) ----------------
// 32 rows/block, 256 blocks. Thread (rg=tid>>5, c=tid&31) computes 4 rows x 1 col.
__global__ __launch_bounds__(256) void gating_logits(
    const float* __restrict__ x, const float* __restrict__ wg,
    const float* __restrict__ wn, float* __restrict__ cl, float* __restrict__ rn) {
  __shared__ __align__(16) float sx[32][128];
  const int tid = threadIdx.x;
  const int c  = tid & 31;
  const int rg = tid >> 5;          // 0..7, rows rg*4..rg*4+3
  const int rowbase = blockIdx.x * 32;
  const float* wp = (c < 16) ? (wg + c) : (wn + (c - 16));
  float acc[4] = {0.f, 0.f, 0.f, 0.f};
  for (int ch = 0; ch < 8; ++ch) {
    __syncthreads();
    #pragma unroll
    for (int it = 0; it < 4; ++it) {   // stage 32x128 f32 chunk
      const int idx = it * 256 + tid;
      const int r = idx >> 5, co = (idx & 31) * 4;
      *(float4*)&sx[r][co] =
          *(const float4*)(x + (size_t)(rowbase + r) * D_SZ + ch * 128 + co);
    }
    __syncthreads();
    #pragma unroll 4
    for (int d = 0; d < 128; ++d) {
      const float wv = wp[(size_t)(ch * 128 + d) * 16];
      #pragma unroll
      for (int r = 0; r < 4; ++r) acc[r] = fmaf(sx[rg * 4 + r][d], wv, acc[r]);
    }
  }
  #pragma unroll
  for (int r = 0; r < 4; ++r) {
    const int row = rowbase + rg * 4 + r;
    if (c < 16) cl[(size_t)row * 16 + c] = acc[r];
    else        rn[(size_t)row * 16 + (c - 16)] = acc[r];
  }
}

// ---------------- per-row gating: softmax, top-9, gates, load/importance, lists ----
__global__ __launch_bounds__(256) void gating_post(
    const float* __restrict__ clg, const float* __restrict__ rng,
    const float* __restrict__ noise, float* __restrict__ gates,
    float* __restrict__ stats, int* __restrict__ rowidx, int* __restrict__ rowmap) {
  int* gcount = (int*)(stats + 32);
  __shared__ int lcnt[16];
  __shared__ int lbase[16];
  const int row = blockIdx.x * 256 + threadIdx.x;
  if (threadIdx.x < 16) lcnt[threadIdx.x] = 0;
  float cl[16], sd[16], nl[16], p[16];
  #pragma unroll
  for (int e = 0; e < 16; ++e) {
    cl[e] = clg[(size_t)row * 16 + e];
    const float r = rng[(size_t)row * 16 + e];
    sd[e] = fmaxf(r, 0.0f) + log1pf(expf(-fabsf(r))) + 0.01f;  // softplus + eps
    nl[e] = cl[e] + noise[(size_t)row * 16 + e] * sd[e];
  }
  float mx = nl[0];
  #pragma unroll
  for (int e = 1; e < 16; ++e) mx = fmaxf(mx, nl[e]);
  float sum = 0.0f;
  #pragma unroll
  for (int e = 0; e < 16; ++e) { p[e] = expf(nl[e] - mx); sum += p[e]; }
  const float inv = 1.0f / sum;
  #pragma unroll
  for (int e = 0; e < 16; ++e) p[e] *= inv;
  // top-9 selection (ties -> lowest index, matches lax.top_k)
  float tmp[16];
  #pragma unroll
  for (int e = 0; e < 16; ++e) tmp[e] = p[e];
  float tv[9]; int ti[9];
  for (int k = 0; k < 9; ++k) {
    float bv = tmp[0]; int bj = 0;
    #pragma unroll
    for (int j = 1; j < 16; ++j) if (tmp[j] > bv) { bv = tmp[j]; bj = j; }
    tv[k] = bv; ti[k] = bj; tmp[bj] = -1.0f;
  }
  float s8 = 0.0f;
  #pragma unroll
  for (int k = 0; k < 8; ++k) s8 += tv[k];
  const float denom = s8 + 1e-6f;
  float g[16];
  #pragma unroll
  for (int e = 0; e < 16; ++e) g[e] = 0.0f;
  for (int k = 0; k < 8; ++k) g[ti[k]] = tv[k] / denom;
  const float thr_in = tv[8], thr_out = tv[7];
  float lc[16];
  #pragma unroll
  for (int e = 0; e < 16; ++e) {
    const float t = (nl[e] > thr_in) ? thr_in : thr_out;
    lc[e] = 0.5f * (1.0f + erff(((cl[e] - t) / sd[e]) * 0.70710678118654752f));
  }
  #pragma unroll
  for (int e = 0; e < 16; ++e) gates[(size_t)row * 16 + e] = g[e];
  // ---- expert assignment lists ----
  __syncthreads();
  int myslot[8];
  #pragma unroll
  for (int k = 0; k < 8; ++k) myslot[k] = atomicAdd(&lcnt[ti[k]], 1);
  __syncthreads();
  if (threadIdx.x < 16) lbase[threadIdx.x] = atomicAdd(&gcount[threadIdx.x], lcnt[threadIdx.x]);
  __syncthreads();
  #pragma unroll
  for (int k = 0; k < 8; ++k) {
    const int e = ti[k];
    const int slot = lbase[e] + myslot[k];
    rowidx[e * B_SZ + slot] = row;
    rowmap[row * 8 + k] = (e << 13) | slot;
  }
  // ---- importance / load partial sums: wave-reduce then one atomic per wave ----
  #pragma unroll
  for (int e = 0; e < 16; ++e) {
    float vi = g[e], vl = lc[e];
    for (int o = 32; o > 0; o >>= 1) { vi += __shfl_down(vi, o); vl += __shfl_down(vl, o); }
    if ((threadIdx.x & 63) == 0) {
      atomicAdd(&stats[e], vi);
      atomicAdd(&stats[16 + e], vl);
    }
  }
}

// ---------------- tile table + partial-buffer base scan ----------------
__global__ void setup_k(const float* __restrict__ stats, int* __restrict__ tileTable,
                        int* __restrict__ pbase) {
  if (threadIdx.x == 0) {
    const int* gcount = (const int*)(stats + 32);
    int t = 0, pb = 0;
    for (int e = 0; e < 16; ++e) {
      pbase[e] = pb;
      const int c = gcount[e];
      const int nt = (c + 127) >> 7;
      pb += nt << 7;
      for (int i = 0; i < nt; ++i) tileTable[t++] = (e << 16) | i;
    }
    for (; t < MAXTILES; ++t) tileTable[t] = -1;
  }
}

// ---------------- sparse gather GEMM: partial[pslot] = g * (Xb[rows] @ We^T) ------
__global__ __launch_bounds__(256, 3) void moe_gemm(
    const unsigned short* __restrict__ Xb,   // [B][D] bf16
    const unsigned short* __restrict__ Wt,   // [E][H][D] bf16
    const float* __restrict__ gates,         // [B][E]
    const float* __restrict__ stats,         // counts at +32
    const int* __restrict__ rowidx,          // [E][B]
    const int* __restrict__ tileTable, const int* __restrict__ pbase,
    unsigned short* __restrict__ partial) {  // [padded slots][H] bf16
  __shared__ __align__(16) unsigned short sA[128 * 64];
  __shared__ __align__(16) unsigned short sB[128 * 64];
  __shared__ float sGG[128];
  __shared__ int   sRI[128];

  const int tt = tileTable[blockIdx.x];
  if (tt < 0) return;
  const int e = tt >> 16, tile = tt & 0xFFFF;
  const int slot0 = tile << 7;
  const int cnt = ((const int*)(stats + 32))[e];
  const int col0 = blockIdx.y << 7;

  const int tid  = threadIdx.x;
  const int lane = tid & 63;
  const int wave = tid >> 6;
  const int wm = wave >> 1, wn = wave & 1;
  const int ml = lane & 15;
  const int quad = lane >> 4;
  const int wbase = tid & ~63;

  if (tid < 128) {
    const int slot = slot0 + tid;
    const int ok = slot < cnt;
    const int row = ok ? rowidx[e * B_SZ + slot] : 0;
    sRI[tid] = row;
    sGG[tid] = ok ? gates[(size_t)row * 16 + e] : 0.0f;
  }
  __syncthreads();

  // per-i staging source pointers (row gather for A, n-major for B)
  const unsigned short* We = Wt + (size_t)e * D_SZ * H_SZ;
  const unsigned short* aptr[4];
  const unsigned short* bptr[4];
  #pragma unroll
  for (int i = 0; i < 4; ++i) {
    const int s = i * 256 + tid;
    const int m = s >> 3, pp = s & 7;
    const int gcA = pp ^ (m & 7);
    aptr[i] = Xb + (size_t)sRI[m] * D_SZ + gcA * 8;
    const int n = m;                      // same index math for B tile
    const int gcB = pp ^ (n & 7);
    bptr[i] = We + (size_t)(col0 + n) * D_SZ + gcB * 8;
  }

  f32x4 acc[4][4] = {};
  for (int kb = 0; kb < 16; ++kb) {
    const int k0 = kb * 64;
    __syncthreads();  // previous iter's LDS reads done
    #pragma unroll
    for (int i = 0; i < 4; ++i)
      async_ld16(sA + (size_t)(i * 256 + wbase) * 8, aptr[i] + k0);
    #pragma unroll
    for (int i = 0; i < 4; ++i)
      async_ld16(sB + (size_t)(i * 256 + wbase) * 8, bptr[i] + k0);
    __syncthreads();  // staging visible
    #pragma unroll
    for (int kk = 0; kk < 2; ++kk) {
      short8 af[4], bfr[4];
      #pragma unroll
      for (int i = 0; i < 4; ++i) {
        const int m = wm * 64 + i * 16 + ml;
        const int cA = kk * 4 + quad;
        af[i]  = *(const short8*)(sA + ((size_t)m * 8 + (cA ^ (m & 7))) * 8);
        const int n = wn * 64 + i * 16 + ml;
        bfr[i] = *(const short8*)(sB + ((size_t)n * 8 + (cA ^ (n & 7))) * 8);
      }
      #pragma unroll
      for (int i = 0; i < 4; ++i)
        #pragma unroll
        for (int j = 0; j < 4; ++j)
          acc[i][j] = __builtin_amdgcn_mfma_f32_16x16x32_bf16(af[i], bfr[j], acc[i][j], 0, 0, 0);
    }
  }

  // epilogue: gate-scale, write bf16 partial rows (C layout: col=lane&15, row=quad*4+r)
  const int pb = pbase[e];
  #pragma unroll
  for (int i = 0; i < 4; ++i) {
    const int mbase = wm * 64 + i * 16 + quad * 4;
    #pragma unroll
    for (int r = 0; r < 4; ++r) {
      const int mrow = mbase + r;
      const float gv = sGG[mrow];
      const size_t prow = (size_t)(pb + slot0 + mrow);
      #pragma unroll
      for (int j = 0; j < 4; ++j) {
        const int cc = wn * 64 + j * 16 + ml;
        partial[prow * H_SZ + col0 + cc] = f2bf(acc[i][j][r] * gv);
      }
    }
  }
}

// ---------------- per-row reduce of 8 partials + bias ----------------
__global__ __launch_bounds__(256) void reduce_k(
    const unsigned short* __restrict__ partial, const int* __restrict__ rowmap,
    const int* __restrict__ pbase, const float* __restrict__ gates,
    const float* __restrict__ ebias, float* __restrict__ y) {
  const int row = blockIdx.x;
  const int tid = threadIdx.x;
  __shared__ int sp[8];
  __shared__ float sg[16];
  if (tid < 8) {
    const int v = rowmap[row * 8 + tid];
    sp[tid] = pbase[v >> 13] + (v & 8191);
  }
  if (tid < 16) sg[tid] = gates[(size_t)row * 16 + tid];
  __syncthreads();
  const int c0 = tid * 4;
  float a0 = 0.f, a1 = 0.f, a2 = 0.f, a3 = 0.f;
  #pragma unroll
  for (int k = 0; k < 8; ++k) {
    const ushort4 pv = *(const ushort4*)(partial + (size_t)sp[k] * H_SZ + c0);
    a0 += bf2f(pv.x); a1 += bf2f(pv.y); a2 += bf2f(pv.z); a3 += bf2f(pv.w);
  }
  #pragma unroll
  for (int e = 0; e < 16; ++e) {
    const float gv = sg[e];
    const float4 bb = *(const float4*)(ebias + (size_t)e * H_SZ + c0);
    a0 = fmaf(gv, bb.x, a0); a1 = fmaf(gv, bb.y, a1);
    a2 = fmaf(gv, bb.z, a2); a3 = fmaf(gv, bb.w, a3);
  }
  float4 out = {a0, a1, a2, a3};
  *(float4*)(y + (size_t)row * H_SZ + c0) = out;
}

// ---------------- loss finalize ----------------
__global__ void loss_k(const float* __restrict__ stats, float* __restrict__ out) {
  if (threadIdx.x == 0) {
    double si = 0.0, sl = 0.0;
    for (int e = 0; e < 16; ++e) { si += stats[e]; sl += stats[16 + e]; }
    const double mi = si / 16.0, mld = sl / 16.0;
    double vi = 0.0, vl = 0.0;
    for (int e = 0; e < 16; ++e) {
      const double di = stats[e] - mi;       vi += di * di;
      const double dl = stats[16 + e] - mld; vl += dl * dl;
    }
    vi /= 15.0; vl /= 15.0;  // ddof=1
    const double loss = 0.01 * (vi / (mi * mi + 1e-10) + vl / (mld * mld + 1e-10));
    out[(size_t)B_SZ * H_SZ] = (float)loss;
  }
}

extern "C" void kernel_launch(void* const* d_in, const int* in_sizes, int n_in,
                              void* d_out, int out_size, void* d_ws, size_t ws_size,
                              hipStream_t stream) {
  (void)in_sizes; (void)n_in; (void)out_size; (void)ws_size;
  const float* x    = (const float*)d_in[0];
  const float* wg   = (const float*)d_in[1];
  const float* wnoi = (const float*)d_in[2];
  const float* ew   = (const float*)d_in[3];
  const float* eb   = (const float*)d_in[4];
  const float* nz   = (const float*)d_in[5];
  float* y = (float*)d_out;

  char* ws = (char*)d_ws;
  const size_t MB = 1024 * 1024;
  unsigned short* xb     = (unsigned short*)(ws);                 // 16 MB
  unsigned short* wtb    = (unsigned short*)(ws + 16 * MB);       // 32 MB
  float* cl              = (float*)(ws + 48 * MB);                // 512 KB
  float* rn              = (float*)(ws + 48 * MB + 512 * 1024);   // 512 KB
  float* gates           = (float*)(ws + 49 * MB);                // 512 KB
  int*   rowidx          = (int*)  (ws + 49 * MB + 512 * 1024);   // 512 KB
  int*   rowmap          = (int*)  (ws + 50 * MB);                // 256 KB
  float* stats           = (float*)(ws + 50 * MB + 512 * 1024);   // 48 f32 + counts
  int*   tileTable       = (int*)  (ws + 50 * MB + 768 * 1024);   // 544 ints
  int*   pbase           = (int*)  (ws + 50 * MB + 768 * 1024 + 4096);  // 16 ints
  unsigned short* partial= (unsigned short*)(ws + 52 * MB);       // ~132 MB

  hipLaunchKernelGGL(xcast,         dim3(8192),       dim3(256), 0, stream, x, xb, stats);
  hipLaunchKernelGGL(wtconv,        dim3(16, 16, 16), dim3(256), 0, stream, ew, wtb);
  hipLaunchKernelGGL(gating_logits, dim3(256),        dim3(256), 0, stream, x, wg, wnoi, cl, rn);
  hipLaunchKernelGGL(gating_post,   dim3(32),         dim3(256), 0, stream, cl, rn, nz, gates, stats, rowidx, rowmap);
  hipLaunchKernelGGL(setup_k,       dim3(1),          dim3(64),  0, stream, stats, tileTable, pbase);
  hipLaunchKernelGGL(moe_gemm,      dim3(MAXTILES, 8),dim3(256), 0, stream, xb, wtb, gates, stats, rowidx, tileTable, pbase, partial);
  hipLaunchKernelGGL(reduce_k,      dim3(8192),       dim3(256), 0, stream, partial, rowmap, pbase, gates, eb, y);
  hipLaunchKernelGGL(loss_k,        dim3(1),          dim3(64),  0, stream, stats, y);
}

// Round 3
// 499.632 us; speedup vs baseline: 1.0680x; 1.0680x over previous
//
#include <hip/hip_runtime.h>
#include <cstdint>

#define B_SZ 8192
#define D_SZ 1024
#define E_SZ 16
#define H_SZ 1024
#define MAXTILES 544   // >= sum_e ceil(count_e/128) worst case (512+16)

using short8 = __attribute__((ext_vector_type(8))) short;
using f32x4  = __attribute__((ext_vector_type(4))) float;

__device__ __forceinline__ unsigned short f2bf(float f) {
  union { float f; unsigned int u; } v; v.f = f;
  unsigned int u = v.u;
  return (unsigned short)((u + 0x7fffu + ((u >> 16) & 1u)) >> 16);  // RNE
}
__device__ __forceinline__ float bf2f(unsigned short h) {
  union { unsigned int u; float f; } v; v.u = ((unsigned int)h) << 16; return v.f;
}

__device__ __forceinline__ void async_ld16(void* lds, const void* g) {
  __builtin_amdgcn_global_load_lds(
      reinterpret_cast<const unsigned int __attribute__((address_space(1)))*>(
          reinterpret_cast<uintptr_t>(g)),
      reinterpret_cast<unsigned int __attribute__((address_space(3)))*>(
          reinterpret_cast<uintptr_t>(lds)),
      16, 0, 0);
}

// ============ prep: fused xcast + wtconv + gating_logits ============
// blocks [0,256): gating_logits; [256,8448): xcast; [8448,12544): wtconv
__global__ __launch_bounds__(256) void prep(
    const float* __restrict__ x, const float* __restrict__ wg,
    const float* __restrict__ wn, const float* __restrict__ ew,
    unsigned short* __restrict__ xb, unsigned short* __restrict__ wtb,
    float* __restrict__ cl, float* __restrict__ rn, float* __restrict__ stats) {
  __shared__ __align__(16) char psm[16640];
  const int bx = blockIdx.x;
  const int tid = threadIdx.x;

  if (bx < 256) {
    // ---- gating_logits: 32 rows/block, thread (rg,c) does 4 rows x 1 col ----
    float (*sx)[128] = (float(*)[128])psm;
    const int c  = tid & 31;
    const int rg = tid >> 5;
    const int rowbase = bx * 32;
    const float* wp = (c < 16) ? (wg + c) : (wn + (c - 16));
    float acc[4] = {0.f, 0.f, 0.f, 0.f};
    for (int ch = 0; ch < 8; ++ch) {
      __syncthreads();
      #pragma unroll
      for (int it = 0; it < 4; ++it) {
        const int idx = it * 256 + tid;
        const int r = idx >> 5, co = (idx & 31) * 4;
        *(float4*)&sx[r][co] =
            *(const float4*)(x + (size_t)(rowbase + r) * D_SZ + ch * 128 + co);
      }
      __syncthreads();
      #pragma unroll 4
      for (int d = 0; d < 128; ++d) {
        const float wv = wp[(size_t)(ch * 128 + d) * 16];
        #pragma unroll
        for (int r = 0; r < 4; ++r) acc[r] = fmaf(sx[rg * 4 + r][d], wv, acc[r]);
      }
    }
    #pragma unroll
    for (int r = 0; r < 4; ++r) {
      const int row = rowbase + rg * 4 + r;
      if (c < 16) cl[(size_t)row * 16 + c] = acc[r];
      else        rn[(size_t)row * 16 + (c - 16)] = acc[r];
    }
  } else if (bx < 8448) {
    // ---- xcast: fp32 -> bf16 ----
    const int b = bx - 256;
    const size_t i = (size_t)b * 256 + tid;  // float4 index
    float4 v = ((const float4*)x)[i];
    unsigned long long r = (unsigned long long)f2bf(v.x)
        | ((unsigned long long)f2bf(v.y) << 16)
        | ((unsigned long long)f2bf(v.z) << 32)
        | ((unsigned long long)f2bf(v.w) << 48);
    ((unsigned long long*)xb)[i] = r;
    if (b == 0 && tid < 48) stats[tid] = 0.0f;
  } else {
    // ---- wtconv: expert_w (E,D,H) fp32 -> Wt (E,H,D) bf16 ----
    float (*t)[65] = (float(*)[65])psm;
    const int b = bx - 8448;
    const int e  = b >> 8;
    const int d0 = ((b >> 4) & 15) * 64;
    const int h0 = (b & 15) * 64;
    const float* We = ew + (size_t)e * D_SZ * H_SZ;
    unsigned short* Wte = wtb + (size_t)e * D_SZ * H_SZ;
    #pragma unroll
    for (int i = 0; i < 16; ++i) {
      const int idx = i * 256 + tid;
      const int r = idx >> 6, cc = idx & 63;
      t[r][cc] = We[(size_t)(d0 + r) * H_SZ + h0 + cc];
    }
    __syncthreads();
    #pragma unroll
    for (int i = 0; i < 16; ++i) {
      const int idx = i * 256 + tid;
      const int r = idx >> 6, cc = idx & 63;
      Wte[(size_t)(h0 + r) * D_SZ + d0 + cc] = f2bf(t[cc][r]);
    }
  }
}

// ---------------- per-row gating: softmax, top-9, gates, load/importance, lists ----
__global__ __launch_bounds__(64) void gating_post(
    const float* __restrict__ clg, const float* __restrict__ rng,
    const float* __restrict__ noise, float* __restrict__ gates,
    float* __restrict__ stats, int* __restrict__ rowidx, int* __restrict__ rowmap) {
  int* gcount = (int*)(stats + 32);
  __shared__ int lcnt[16];
  __shared__ int lbase[16];
  const int row = blockIdx.x * 64 + threadIdx.x;
  if (threadIdx.x < 16) lcnt[threadIdx.x] = 0;
  float cl[16], sd[16], nl[16], p[16];
  #pragma unroll
  for (int e = 0; e < 16; ++e) {
    cl[e] = clg[(size_t)row * 16 + e];
    const float r = rng[(size_t)row * 16 + e];
    sd[e] = fmaxf(r, 0.0f) + log1pf(expf(-fabsf(r))) + 0.01f;  // softplus + eps
    nl[e] = cl[e] + noise[(size_t)row * 16 + e] * sd[e];
  }
  float mx = nl[0];
  #pragma unroll
  for (int e = 1; e < 16; ++e) mx = fmaxf(mx, nl[e]);
  float sum = 0.0f;
  #pragma unroll
  for (int e = 0; e < 16; ++e) { p[e] = expf(nl[e] - mx); sum += p[e]; }
  const float inv = 1.0f / sum;
  #pragma unroll
  for (int e = 0; e < 16; ++e) p[e] *= inv;
  // top-9 selection (ties -> lowest index, matches lax.top_k)
  float tmp[16];
  #pragma unroll
  for (int e = 0; e < 16; ++e) tmp[e] = p[e];
  float tv[9]; int ti[9];
  for (int k = 0; k < 9; ++k) {
    float bv = tmp[0]; int bj = 0;
    #pragma unroll
    for (int j = 1; j < 16; ++j) if (tmp[j] > bv) { bv = tmp[j]; bj = j; }
    tv[k] = bv; ti[k] = bj; tmp[bj] = -1.0f;
  }
  float s8 = 0.0f;
  #pragma unroll
  for (int k = 0; k < 8; ++k) s8 += tv[k];
  const float denom = s8 + 1e-6f;
  float g[16];
  #pragma unroll
  for (int e = 0; e < 16; ++e) g[e] = 0.0f;
  for (int k = 0; k < 8; ++k) g[ti[k]] = tv[k] / denom;
  const float thr_in = tv[8], thr_out = tv[7];
  float lc[16];
  #pragma unroll
  for (int e = 0; e < 16; ++e) {
    const float t = (nl[e] > thr_in) ? thr_in : thr_out;
    lc[e] = 0.5f * (1.0f + erff(((cl[e] - t) / sd[e]) * 0.70710678118654752f));
  }
  #pragma unroll
  for (int e = 0; e < 16; ++e) gates[(size_t)row * 16 + e] = g[e];
  // ---- expert assignment lists ----
  __syncthreads();
  int myslot[8];
  #pragma unroll
  for (int k = 0; k < 8; ++k) myslot[k] = atomicAdd(&lcnt[ti[k]], 1);
  __syncthreads();
  if (threadIdx.x < 16) lbase[threadIdx.x] = atomicAdd(&gcount[threadIdx.x], lcnt[threadIdx.x]);
  __syncthreads();
  #pragma unroll
  for (int k = 0; k < 8; ++k) {
    const int e = ti[k];
    const int slot = lbase[e] + myslot[k];
    rowidx[e * B_SZ + slot] = row;
    rowmap[row * 8 + k] = (e << 13) | slot;
  }
  // ---- importance / load partial sums: wave-reduce then one atomic per wave ----
  #pragma unroll
  for (int e = 0; e < 16; ++e) {
    float vi = g[e], vl = lc[e];
    for (int o = 32; o > 0; o >>= 1) { vi += __shfl_down(vi, o); vl += __shfl_down(vl, o); }
    if (threadIdx.x == 0) {
      atomicAdd(&stats[e], vi);
      atomicAdd(&stats[16 + e], vl);
    }
  }
}

// ---------------- sparse gather GEMM: partial[pslot] = g * (Xb[rows] @ We^T) ------
__global__ __launch_bounds__(256, 4) void moe_gemm(
    const unsigned short* __restrict__ Xb,   // [B][D] bf16
    const unsigned short* __restrict__ Wt,   // [E][H][D] bf16
    const float* __restrict__ gates,         // [B][E]
    const float* __restrict__ stats,         // counts at +32
    const int* __restrict__ rowidx,          // [E][B]
    unsigned short* __restrict__ partial) {  // [padded slots][H] bf16
  // LDS: sOut [0,34816) overlays sA [0,16384) + sB [16384,32768)
  __shared__ __align__(16) char smem[34816 + 512 + 512];
  unsigned short* sA = (unsigned short*)smem;
  unsigned short* sB = (unsigned short*)(smem + 16384);
  unsigned short* sOut = (unsigned short*)smem;          // 128 x 136 ushorts
  float* sGG = (float*)(smem + 34816);
  int*   sRI = (int*)(smem + 34816 + 512);

  // ---- self-scan: find (expert, tile) for this block ----
  const int* gcount = (const int*)(stats + 32);
  int my_e = -1, tile = 0, tstart = 0, acc_t = 0;
  #pragma unroll
  for (int ee = 0; ee < 16; ++ee) {
    const int nt_e = (gcount[ee] + 127) >> 7;
    if (my_e < 0 && (int)blockIdx.x < acc_t + nt_e) {
      my_e = ee; tile = blockIdx.x - acc_t; tstart = acc_t;
    }
    acc_t += nt_e;
  }
  if (my_e < 0) return;
  const int e = my_e;
  const int slot0 = tile << 7;
  const int cnt = gcount[e];
  const int col0 = blockIdx.y << 7;
  const int pb = tstart << 7;   // padded partial base for this expert

  const int tid  = threadIdx.x;
  const int lane = tid & 63;
  const int wave = tid >> 6;
  const int wm = wave >> 1, wn = wave & 1;
  const int ml = lane & 15;
  const int quad = lane >> 4;
  const int wbase = tid & ~63;

  if (tid < 128) {
    const int slot = slot0 + tid;
    const int ok = slot < cnt;
    const int row = ok ? rowidx[e * B_SZ + slot] : 0;
    sRI[tid] = row;
    sGG[tid] = ok ? gates[(size_t)row * 16 + e] : 0.0f;
  }
  __syncthreads();

  // per-i staging source pointers (row gather for A, n-major for B)
  const unsigned short* We = Wt + (size_t)e * D_SZ * H_SZ;
  const unsigned short* aptr[4];
  const unsigned short* bptr[4];
  #pragma unroll
  for (int i = 0; i < 4; ++i) {
    const int s = i * 256 + tid;
    const int m = s >> 3, pp = s & 7;
    const int gcA = pp ^ (m & 7);
    aptr[i] = Xb + (size_t)sRI[m] * D_SZ + gcA * 8;
    const int gcB = pp ^ (m & 7);
    bptr[i] = We + (size_t)(col0 + m) * D_SZ + gcB * 8;
  }

  f32x4 acc[4][4] = {};
  for (int kb = 0; kb < 16; ++kb) {
    const int k0 = kb * 64;
    __syncthreads();  // previous iter's LDS reads done
    #pragma unroll
    for (int i = 0; i < 4; ++i)
      async_ld16(sA + (size_t)(i * 256 + wbase) * 8, aptr[i] + k0);
    #pragma unroll
    for (int i = 0; i < 4; ++i)
      async_ld16(sB + (size_t)(i * 256 + wbase) * 8, bptr[i] + k0);
    __syncthreads();  // staging visible
    #pragma unroll
    for (int kk = 0; kk < 2; ++kk) {
      short8 af[4], bfr[4];
      #pragma unroll
      for (int i = 0; i < 4; ++i) {
        const int m = wm * 64 + i * 16 + ml;
        const int cA = kk * 4 + quad;
        af[i]  = *(const short8*)(sA + ((size_t)m * 8 + (cA ^ (m & 7))) * 8);
        const int n = wn * 64 + i * 16 + ml;
        bfr[i] = *(const short8*)(sB + ((size_t)n * 8 + (cA ^ (n & 7))) * 8);
      }
      #pragma unroll
      for (int i = 0; i < 4; ++i)
        #pragma unroll
        for (int j = 0; j < 4; ++j)
          acc[i][j] = __builtin_amdgcn_mfma_f32_16x16x32_bf16(af[i], bfr[j], acc[i][j], 0, 0, 0);
    }
  }

  // ---- epilogue: gate-scale -> LDS tile (stride 136) -> full-line nt stores ----
  __syncthreads();  // all waves done reading sA/sB
  #pragma unroll
  for (int i = 0; i < 4; ++i) {
    const int mbase = wm * 64 + i * 16 + quad * 4;
    #pragma unroll
    for (int r = 0; r < 4; ++r) {
      const int mrow = mbase + r;
      const float gv = sGG[mrow];
      #pragma unroll
      for (int j = 0; j < 4; ++j) {
        const int cc = wn * 64 + j * 16 + ml;
        sOut[mrow * 136 + cc] = f2bf(acc[i][j][r] * gv);
      }
    }
  }
  __syncthreads();
  const size_t prow0 = (size_t)(pb + slot0);
  #pragma unroll
  for (int it = 0; it < 8; ++it) {
    const int s = it * 256 + tid;
    const int rr = s >> 4;
    const int c8 = (s & 15) * 8;
    const short8 v = *(const short8*)(sOut + rr * 136 + c8);
    __builtin_nontemporal_store(
        v, (short8*)(partial + (prow0 + rr) * H_SZ + col0 + c8));
  }
}

// ---------------- per-row reduce of 8 partials + bias (+ loss finalize) ----------
__global__ __launch_bounds__(256) void reduce_k(
    const unsigned short* __restrict__ partial, const int* __restrict__ rowmap,
    const float* __restrict__ stats, const float* __restrict__ gates,
    const float* __restrict__ ebias, float* __restrict__ y) {
  const int row = blockIdx.x;
  const int tid = threadIdx.x;
  const int* gcount = (const int*)(stats + 32);
  __shared__ int sp[8];
  __shared__ float sg[16];
  if (tid < 8) {
    const int v = rowmap[row * 8 + tid];
    const int e = v >> 13, slot = v & 8191;
    int t = 0;
    #pragma unroll
    for (int ee = 0; ee < 16; ++ee) t += (ee < e) ? ((gcount[ee] + 127) >> 7) : 0;
    sp[tid] = (t << 7) + slot;
  }
  if (tid < 16) sg[tid] = gates[(size_t)row * 16 + tid];
  __syncthreads();
  const int c0 = tid * 4;
  float a0 = 0.f, a1 = 0.f, a2 = 0.f, a3 = 0.f;
  #pragma unroll
  for (int k = 0; k < 8; ++k) {
    const ushort4 pv = *(const ushort4*)(partial + (size_t)sp[k] * H_SZ + c0);
    a0 += bf2f(pv.x); a1 += bf2f(pv.y); a2 += bf2f(pv.z); a3 += bf2f(pv.w);
  }
  #pragma unroll
  for (int e = 0; e < 16; ++e) {
    const float gv = sg[e];
    const float4 bb = *(const float4*)(ebias + (size_t)e * H_SZ + c0);
    a0 = fmaf(gv, bb.x, a0); a1 = fmaf(gv, bb.y, a1);
    a2 = fmaf(gv, bb.z, a2); a3 = fmaf(gv, bb.w, a3);
  }
  float4 out = {a0, a1, a2, a3};
  *(float4*)(y + (size_t)row * H_SZ + c0) = out;

  // ---- loss finalize (one thread of one block) ----
  if (blockIdx.x == 0 && tid == 0) {
    double si = 0.0, sl = 0.0;
    for (int e = 0; e < 16; ++e) { si += stats[e]; sl += stats[16 + e]; }
    const double mi = si / 16.0, mld = sl / 16.0;
    double vi = 0.0, vl = 0.0;
    for (int e = 0; e < 16; ++e) {
      const double di = stats[e] - mi;       vi += di * di;
      const double dl = stats[16 + e] - mld; vl += dl * dl;
    }
    vi /= 15.0; vl /= 15.0;  // ddof=1
    const double loss = 0.01 * (vi / (mi * mi + 1e-10) + vl / (mld * mld + 1e-10));
    y[(size_t)B_SZ * H_SZ] = (float)loss;
  }
}

extern "C" void kernel_launch(void* const* d_in, const int* in_sizes, int n_in,
                              void* d_out, int out_size, void* d_ws, size_t ws_size,
                              hipStream_t stream) {
  (void)in_sizes; (void)n_in; (void)out_size; (void)ws_size;
  const float* x    = (const float*)d_in[0];
  const float* wg   = (const float*)d_in[1];
  const float* wnoi = (const float*)d_in[2];
  const float* ew   = (const float*)d_in[3];
  const float* eb   = (const float*)d_in[4];
  const float* nz   = (const float*)d_in[5];
  float* y = (float*)d_out;

  char* ws = (char*)d_ws;
  const size_t MB = 1024 * 1024;
  unsigned short* xb     = (unsigned short*)(ws);                 // 16 MB
  unsigned short* wtb    = (unsigned short*)(ws + 16 * MB);       // 32 MB
  float* cl              = (float*)(ws + 48 * MB);                // 512 KB
  float* rn              = (float*)(ws + 48 * MB + 512 * 1024);   // 512 KB
  float* gates           = (float*)(ws + 49 * MB);                // 512 KB
  int*   rowidx          = (int*)  (ws + 49 * MB + 512 * 1024);   // 512 KB
  int*   rowmap          = (int*)  (ws + 50 * MB);                // 256 KB
  float* stats           = (float*)(ws + 50 * MB + 512 * 1024);   // 32 f32 + 16 counts
  unsigned short* partial= (unsigned short*)(ws + 52 * MB);       // ~143 MB

  hipLaunchKernelGGL(prep,        dim3(12544),      dim3(256), 0, stream,
                     x, wg, wnoi, ew, xb, wtb, cl, rn, stats);
  hipLaunchKernelGGL(gating_post, dim3(128),        dim3(64),  0, stream,
                     cl, rn, nz, gates, stats, rowidx, rowmap);
  hipLaunchKernelGGL(moe_gemm,    dim3(MAXTILES, 8), dim3(256), 0, stream,
                     xb, wtb, gates, stats, rowidx, partial);
  hipLaunchKernelGGL(reduce_k,    dim3(8192),       dim3(256), 0, stream,
                     partial, rowmap, stats, gates, eb, y);
}

// Round 4
// 476.891 us; speedup vs baseline: 1.1189x; 1.0477x over previous
//
#include <hip/hip_runtime.h>
#include <cstdint>

#define B_SZ 8192
#define D_SZ 1024
#define E_SZ 16
#define H_SZ 1024
#define MAXTILES 544   // >= sum_e ceil(count_e/128) worst case (512+16)

using short8 = __attribute__((ext_vector_type(8))) short;
using f32x4  = __attribute__((ext_vector_type(4))) float;

__device__ __forceinline__ unsigned short f2bf(float f) {
  union { float f; unsigned int u; } v; v.f = f;
  unsigned int u = v.u;
  return (unsigned short)((u + 0x7fffu + ((u >> 16) & 1u)) >> 16);  // RNE
}
__device__ __forceinline__ float bf2f(unsigned short h) {
  union { unsigned int u; float f; } v; v.u = ((unsigned int)h) << 16; return v.f;
}

__device__ __forceinline__ void async_ld16(void* lds, const void* g) {
  __builtin_amdgcn_global_load_lds(
      reinterpret_cast<const unsigned int __attribute__((address_space(1)))*>(
          reinterpret_cast<uintptr_t>(g)),
      reinterpret_cast<unsigned int __attribute__((address_space(3)))*>(
          reinterpret_cast<uintptr_t>(lds)),
      16, 0, 0);
}

// ============ prep: fused gating_logits + xcast + wtconv ============
// blocks [0,512): gating_logits (16 rows each)
// blocks [512,4608): xcast (8 floats/thread)
// blocks [4608,8704): wtconv (vectorized transpose)
__global__ __launch_bounds__(256) void prep(
    const float* __restrict__ x, const float* __restrict__ wg,
    const float* __restrict__ wn, const float* __restrict__ ew,
    unsigned short* __restrict__ xb, unsigned short* __restrict__ wtb,
    float* __restrict__ cl, float* __restrict__ rn, float* __restrict__ stats) {
  __shared__ __align__(16) char psm[16640];
  const int bx = blockIdx.x;
  const int tid = threadIdx.x;

  if (bx < 512) {
    // ---- gating_logits: 16 rows/block, thread (rg,c) does 2 rows x 1 col ----
    float (*sx)[128] = (float(*)[128])psm;
    const int c  = tid & 31;
    const int rg = tid >> 5;            // 0..7 -> rows rg*2, rg*2+1
    const int rowbase = bx * 16;
    const float* wp = (c < 16) ? (wg + c) : (wn + (c - 16));
    float acc0 = 0.f, acc1 = 0.f;
    for (int ch = 0; ch < 8; ++ch) {
      __syncthreads();
      #pragma unroll
      for (int it = 0; it < 2; ++it) {   // stage 16x128 f32 chunk
        const int idx = it * 256 + tid;
        const int r = idx >> 5, co = (idx & 31) * 4;
        *(float4*)&sx[r][co] =
            *(const float4*)(x + (size_t)(rowbase + r) * D_SZ + ch * 128 + co);
      }
      __syncthreads();
      #pragma unroll 4
      for (int d = 0; d < 128; ++d) {
        const float wv = wp[(size_t)(ch * 128 + d) * 16];
        acc0 = fmaf(sx[rg * 2][d],     wv, acc0);
        acc1 = fmaf(sx[rg * 2 + 1][d], wv, acc1);
      }
    }
    const int row0 = rowbase + rg * 2;
    if (c < 16) {
      cl[(size_t)row0 * 16 + c] = acc0;
      cl[(size_t)(row0 + 1) * 16 + c] = acc1;
    } else {
      rn[(size_t)row0 * 16 + (c - 16)] = acc0;
      rn[(size_t)(row0 + 1) * 16 + (c - 16)] = acc1;
    }
  } else if (bx < 4608) {
    // ---- xcast: fp32 -> bf16, 8 floats/thread ----
    const int b = bx - 512;
    const size_t i = (size_t)b * 256 + tid;   // short8 index
    const float4 v0 = ((const float4*)x)[2 * i];
    const float4 v1 = ((const float4*)x)[2 * i + 1];
    unsigned short r[8] = {f2bf(v0.x), f2bf(v0.y), f2bf(v0.z), f2bf(v0.w),
                           f2bf(v1.x), f2bf(v1.y), f2bf(v1.z), f2bf(v1.w)};
    ((short8*)xb)[i] = *(const short8*)r;
    if (b == 0 && tid < 48) stats[tid] = 0.0f;
  } else {
    // ---- wtconv: expert_w (E,D,H) fp32 -> Wt (E,H,D) bf16, vectorized ----
    float (*t)[65] = (float(*)[65])psm;
    const int b = bx - 4608;
    const int e  = b >> 8;
    const int d0 = ((b >> 4) & 15) * 64;
    const int h0 = (b & 15) * 64;
    const float* We = ew + (size_t)e * D_SZ * H_SZ;
    unsigned short* Wte = wtb + (size_t)e * D_SZ * H_SZ;
    #pragma unroll
    for (int i = 0; i < 4; ++i) {        // load 64x64 floats, float4
      const int idx = i * 256 + tid;
      const int r = idx >> 4, co = (idx & 15) * 4;
      *(float4*)&t[r][co] =
          *(const float4*)(We + (size_t)(d0 + r) * H_SZ + h0 + co);
    }
    __syncthreads();
    #pragma unroll
    for (int i = 0; i < 2; ++i) {        // store 64 h-rows x 64 d bf16, short8
      const int idx = i * 256 + tid;
      const int r = idx >> 3, c8 = (idx & 7) * 8;
      unsigned short v[8];
      #pragma unroll
      for (int j = 0; j < 8; ++j) v[j] = f2bf(t[c8 + j][r]);
      *(short8*)(Wte + (size_t)(h0 + r) * D_SZ + d0 + c8) = *(const short8*)v;
    }
  }
}

// ---------------- per-row gating: softmax, top-9, gates, load/importance, lists ----
__global__ __launch_bounds__(64) void gating_post(
    const float* __restrict__ clg, const float* __restrict__ rng,
    const float* __restrict__ noise, float* __restrict__ gates,
    float* __restrict__ stats, int* __restrict__ rowidx, int* __restrict__ rowmap) {
  int* gcount = (int*)(stats + 32);
  __shared__ int lcnt[16];
  __shared__ int lbase[16];
  const int row = blockIdx.x * 64 + threadIdx.x;
  if (threadIdx.x < 16) lcnt[threadIdx.x] = 0;
  float cl[16], sd[16], nl[16], p[16];
  #pragma unroll
  for (int e = 0; e < 16; ++e) {
    cl[e] = clg[(size_t)row * 16 + e];
    const float r = rng[(size_t)row * 16 + e];
    sd[e] = fmaxf(r, 0.0f) + log1pf(expf(-fabsf(r))) + 0.01f;  // softplus + eps
    nl[e] = cl[e] + noise[(size_t)row * 16 + e] * sd[e];
  }
  float mx = nl[0];
  #pragma unroll
  for (int e = 1; e < 16; ++e) mx = fmaxf(mx, nl[e]);
  float sum = 0.0f;
  #pragma unroll
  for (int e = 0; e < 16; ++e) { p[e] = expf(nl[e] - mx); sum += p[e]; }
  const float inv = 1.0f / sum;
  #pragma unroll
  for (int e = 0; e < 16; ++e) p[e] *= inv;
  // top-9 selection (ties -> lowest index, matches lax.top_k)
  float tmp[16];
  #pragma unroll
  for (int e = 0; e < 16; ++e) tmp[e] = p[e];
  float tv[9]; int ti[9];
  for (int k = 0; k < 9; ++k) {
    float bv = tmp[0]; int bj = 0;
    #pragma unroll
    for (int j = 1; j < 16; ++j) if (tmp[j] > bv) { bv = tmp[j]; bj = j; }
    tv[k] = bv; ti[k] = bj; tmp[bj] = -1.0f;
  }
  float s8 = 0.0f;
  #pragma unroll
  for (int k = 0; k < 8; ++k) s8 += tv[k];
  const float denom = s8 + 1e-6f;
  float g[16];
  #pragma unroll
  for (int e = 0; e < 16; ++e) g[e] = 0.0f;
  for (int k = 0; k < 8; ++k) g[ti[k]] = tv[k] / denom;
  const float thr_in = tv[8], thr_out = tv[7];
  float lc[16];
  #pragma unroll
  for (int e = 0; e < 16; ++e) {
    const float t = (nl[e] > thr_in) ? thr_in : thr_out;
    lc[e] = 0.5f * (1.0f + erff(((cl[e] - t) / sd[e]) * 0.70710678118654752f));
  }
  #pragma unroll
  for (int e = 0; e < 16; ++e) gates[(size_t)row * 16 + e] = g[e];
  // ---- expert assignment lists ----
  __syncthreads();
  int myslot[8];
  #pragma unroll
  for (int k = 0; k < 8; ++k) myslot[k] = atomicAdd(&lcnt[ti[k]], 1);
  __syncthreads();
  if (threadIdx.x < 16) lbase[threadIdx.x] = atomicAdd(&gcount[threadIdx.x], lcnt[threadIdx.x]);
  __syncthreads();
  #pragma unroll
  for (int k = 0; k < 8; ++k) {
    const int e = ti[k];
    const int slot = lbase[e] + myslot[k];
    rowidx[e * B_SZ + slot] = row;
    rowmap[row * 8 + k] = (e << 13) | slot;
  }
  // ---- importance / load partial sums ----
  #pragma unroll
  for (int e = 0; e < 16; ++e) {
    float vi = g[e], vl = lc[e];
    for (int o = 32; o > 0; o >>= 1) { vi += __shfl_down(vi, o); vl += __shfl_down(vl, o); }
    if (threadIdx.x == 0) {
      atomicAdd(&stats[e], vi);
      atomicAdd(&stats[16 + e], vl);
    }
  }
}

// ---------------- sparse gather GEMM: partial[pslot] = g * (Xb[rows] @ We^T + eb) --
// grid = (8 cols, MAXTILES): col fastest -> same col always maps to the same XCD,
// so each (e,col) B-slice stays L2-resident; 8 cols of one A-tile co-dispatch.
__global__ __launch_bounds__(256, 4) void moe_gemm(
    const unsigned short* __restrict__ Xb,   // [B][D] bf16
    const unsigned short* __restrict__ Wt,   // [E][H][D] bf16
    const float* __restrict__ gates,         // [B][E]
    const float* __restrict__ ebias,         // [E][H]
    const float* __restrict__ stats,         // counts at +32
    const int* __restrict__ rowidx,          // [E][B]
    unsigned short* __restrict__ partial) {  // [padded slots][H] bf16
  // LDS: sOut [0,34816) overlays sA [0,16384) + sB [16384,32768)
  __shared__ __align__(16) char smem[34816 + 512 + 512];
  unsigned short* sA = (unsigned short*)smem;
  unsigned short* sB = (unsigned short*)(smem + 16384);
  unsigned short* sOut = (unsigned short*)smem;          // 128 x 136 ushorts
  float* sGG = (float*)(smem + 34816);
  int*   sRI = (int*)(smem + 34816 + 512);

  // ---- self-scan: find (expert, tile) for this block ----
  const int* gcount = (const int*)(stats + 32);
  int my_e = -1, tile = 0, tstart = 0, acc_t = 0;
  #pragma unroll
  for (int ee = 0; ee < 16; ++ee) {
    const int nt_e = (gcount[ee] + 127) >> 7;
    if (my_e < 0 && (int)blockIdx.y < acc_t + nt_e) {
      my_e = ee; tile = blockIdx.y - acc_t; tstart = acc_t;
    }
    acc_t += nt_e;
  }
  if (my_e < 0) return;
  const int e = my_e;
  const int slot0 = tile << 7;
  const int cnt = gcount[e];
  const int col0 = blockIdx.x << 7;
  const int pb = tstart << 7;   // padded partial base for this expert

  const int tid  = threadIdx.x;
  const int lane = tid & 63;
  const int wave = tid >> 6;
  const int wm = wave >> 1, wn = wave & 1;
  const int ml = lane & 15;
  const int quad = lane >> 4;
  const int wbase = tid & ~63;

  if (tid < 128) {
    const int slot = slot0 + tid;
    const int ok = slot < cnt;
    const int row = ok ? rowidx[e * B_SZ + slot] : 0;
    sRI[tid] = row;
    sGG[tid] = ok ? gates[(size_t)row * 16 + e] : 0.0f;
  }
  // per-thread bias values for the 4 output column fragments (L2-hot)
  float ebv[4];
  #pragma unroll
  for (int j = 0; j < 4; ++j)
    ebv[j] = ebias[(size_t)e * H_SZ + col0 + wn * 64 + j * 16 + ml];
  __syncthreads();

  // per-i staging source pointers (row gather for A, n-major for B)
  const unsigned short* We = Wt + (size_t)e * D_SZ * H_SZ;
  const unsigned short* aptr[4];
  const unsigned short* bptr[4];
  #pragma unroll
  for (int i = 0; i < 4; ++i) {
    const int s = i * 256 + tid;
    const int m = s >> 3, pp = s & 7;
    const int gc = pp ^ (m & 7);
    aptr[i] = Xb + (size_t)sRI[m] * D_SZ + gc * 8;
    bptr[i] = We + (size_t)(col0 + m) * D_SZ + gc * 8;
  }

  f32x4 acc[4][4] = {};
  for (int kb = 0; kb < 16; ++kb) {
    const int k0 = kb * 64;
    __syncthreads();  // previous iter's LDS reads done
    #pragma unroll
    for (int i = 0; i < 4; ++i)
      async_ld16(sA + (size_t)(i * 256 + wbase) * 8, aptr[i] + k0);
    #pragma unroll
    for (int i = 0; i < 4; ++i)
      async_ld16(sB + (size_t)(i * 256 + wbase) * 8, bptr[i] + k0);
    __syncthreads();  // staging visible
    #pragma unroll
    for (int kk = 0; kk < 2; ++kk) {
      short8 af[4], bfr[4];
      #pragma unroll
      for (int i = 0; i < 4; ++i) {
        const int m = wm * 64 + i * 16 + ml;
        const int cA = kk * 4 + quad;
        af[i]  = *(const short8*)(sA + ((size_t)m * 8 + (cA ^ (m & 7))) * 8);
        const int n = wn * 64 + i * 16 + ml;
        bfr[i] = *(const short8*)(sB + ((size_t)n * 8 + (cA ^ (n & 7))) * 8);
      }
      #pragma unroll
      for (int i = 0; i < 4; ++i)
        #pragma unroll
        for (int j = 0; j < 4; ++j)
          acc[i][j] = __builtin_amdgcn_mfma_f32_16x16x32_bf16(af[i], bfr[j], acc[i][j], 0, 0, 0);
    }
  }

  // ---- epilogue: gate*(acc+bias) -> LDS tile (stride 136) -> full-line nt stores
  __syncthreads();  // all waves done reading sA/sB
  #pragma unroll
  for (int i = 0; i < 4; ++i) {
    const int mbase = wm * 64 + i * 16 + quad * 4;
    #pragma unroll
    for (int r = 0; r < 4; ++r) {
      const int mrow = mbase + r;
      const float gv = sGG[mrow];
      #pragma unroll
      for (int j = 0; j < 4; ++j) {
        const int cc = wn * 64 + j * 16 + ml;
        sOut[mrow * 136 + cc] = f2bf(gv * (acc[i][j][r] + ebv[j]));
      }
    }
  }
  __syncthreads();
  const size_t prow0 = (size_t)(pb + slot0);
  #pragma unroll
  for (int it = 0; it < 8; ++it) {
    const int s = it * 256 + tid;
    const int rr = s >> 4;
    const int c8 = (s & 15) * 8;
    const short8 v = *(const short8*)(sOut + rr * 136 + c8);
    __builtin_nontemporal_store(
        v, (short8*)(partial + (prow0 + rr) * H_SZ + col0 + c8));
  }
}

// ---------------- per-row reduce of 8 partials (+ loss finalize) ----------
__global__ __launch_bounds__(128) void reduce_k(
    const unsigned short* __restrict__ partial, const int* __restrict__ rowmap,
    const float* __restrict__ stats, float* __restrict__ y) {
  const int row = blockIdx.x;
  const int tid = threadIdx.x;
  const int* gcount = (const int*)(stats + 32);
  __shared__ int sp[8];
  if (tid < 8) {
    const int v = rowmap[row * 8 + tid];
    const int e = v >> 13, slot = v & 8191;
    int t = 0;
    #pragma unroll
    for (int ee = 0; ee < 16; ++ee) t += (ee < e) ? ((gcount[ee] + 127) >> 7) : 0;
    sp[tid] = (t << 7) + slot;
  }
  __syncthreads();
  const int c0 = tid * 8;
  float a[8] = {0.f, 0.f, 0.f, 0.f, 0.f, 0.f, 0.f, 0.f};
  #pragma unroll
  for (int k = 0; k < 8; ++k) {
    const short8 pv = *(const short8*)(partial + (size_t)sp[k] * H_SZ + c0);
    #pragma unroll
    for (int j = 0; j < 8; ++j) a[j] += bf2f((unsigned short)pv[j]);
  }
  float4 o0 = {a[0], a[1], a[2], a[3]};
  float4 o1 = {a[4], a[5], a[6], a[7]};
  *(float4*)(y + (size_t)row * H_SZ + c0)     = o0;
  *(float4*)(y + (size_t)row * H_SZ + c0 + 4) = o1;

  // ---- loss finalize (one thread of one block) ----
  if (blockIdx.x == 0 && tid == 0) {
    double si = 0.0, sl = 0.0;
    for (int e = 0; e < 16; ++e) { si += stats[e]; sl += stats[16 + e]; }
    const double mi = si / 16.0, mld = sl / 16.0;
    double vi = 0.0, vl = 0.0;
    for (int e = 0; e < 16; ++e) {
      const double di = stats[e] - mi;       vi += di * di;
      const double dl = stats[16 + e] - mld; vl += dl * dl;
    }
    vi /= 15.0; vl /= 15.0;  // ddof=1
    const double loss = 0.01 * (vi / (mi * mi + 1e-10) + vl / (mld * mld + 1e-10));
    y[(size_t)B_SZ * H_SZ] = (float)loss;
  }
}

extern "C" void kernel_launch(void* const* d_in, const int* in_sizes, int n_in,
                              void* d_out, int out_size, void* d_ws, size_t ws_size,
                              hipStream_t stream) {
  (void)in_sizes; (void)n_in; (void)out_size; (void)ws_size;
  const float* x    = (const float*)d_in[0];
  const float* wg   = (const float*)d_in[1];
  const float* wnoi = (const float*)d_in[2];
  const float* ew   = (const float*)d_in[3];
  const float* eb   = (const float*)d_in[4];
  const float* nz   = (const float*)d_in[5];
  float* y = (float*)d_out;

  char* ws = (char*)d_ws;
  const size_t MB = 1024 * 1024;
  unsigned short* xb     = (unsigned short*)(ws);                 // 16 MB
  unsigned short* wtb    = (unsigned short*)(ws + 16 * MB);       // 32 MB
  float* cl              = (float*)(ws + 48 * MB);                // 512 KB
  float* rn              = (float*)(ws + 48 * MB + 512 * 1024);   // 512 KB
  float* gates           = (float*)(ws + 49 * MB);                // 512 KB
  int*   rowidx          = (int*)  (ws + 49 * MB + 512 * 1024);   // 512 KB
  int*   rowmap          = (int*)  (ws + 50 * MB);                // 256 KB
  float* stats           = (float*)(ws + 50 * MB + 512 * 1024);   // 32 f32 + 16 counts
  unsigned short* partial= (unsigned short*)(ws + 52 * MB);       // ~138 MB

  hipLaunchKernelGGL(prep,        dim3(8704),        dim3(256), 0, stream,
                     x, wg, wnoi, ew, xb, wtb, cl, rn, stats);
  hipLaunchKernelGGL(gating_post, dim3(128),         dim3(64),  0, stream,
                     cl, rn, nz, gates, stats, rowidx, rowmap);
  hipLaunchKernelGGL(moe_gemm,    dim3(8, MAXTILES), dim3(256), 0, stream,
                     xb, wtb, gates, eb, stats, rowidx, partial);
  hipLaunchKernelGGL(reduce_k,    dim3(8192),        dim3(128), 0, stream,
                     partial, rowmap, stats, y);
}